// Round 2
// baseline (592.381 us; speedup 1.0000x reference)
//
#include <hip/hip_runtime.h>

#define N_NODES 100000
#define N_EDGES 1600000
#define IN_FEAT 128
#define OUT_FEAT 64
#define LRELU_SLOPE 0.2f
#define EPS_DENOM 1e-16f

// ---- float atomic-max via order-preserving uint encoding ----
__device__ __forceinline__ unsigned int enc_f(float x) {
    unsigned int u = __float_as_uint(x);
    return (u & 0x80000000u) ? ~u : (u | 0x80000000u);
}
__device__ __forceinline__ float dec_f(unsigned int u) {
    u = (u & 0x80000000u) ? (u ^ 0x80000000u) : ~u;
    return __uint_as_float(u);
}
#define ENC_NEG_INF 0x007FFFFFu  // enc_f(-inf)

__global__ __launch_bounds__(256) void init_kernel(unsigned int* __restrict__ e_max_enc,
                                                   float* __restrict__ e_sum) {
    int i = blockIdx.x * 256 + threadIdx.x;
    if (i < N_NODES) {
        e_max_enc[i] = ENC_NEG_INF;
        e_sum[i] = 0.0f;
    }
}

// Wh = x @ W  (100000x128 @ 128x64), fused score_src/score_tgt epilogue.
// Block: 64x4 threads. Each block does 32 rows. Each thread: 8 rows x 1 col.
__global__ __launch_bounds__(256) void gemm_score_kernel(
    const float* __restrict__ x, const float* __restrict__ W,
    const float* __restrict__ a, float* __restrict__ Wh,
    float* __restrict__ s_src, float* __restrict__ s_tgt)
{
    __shared__ float Ws[IN_FEAT * OUT_FEAT];   // 32 KB
    __shared__ float Xs[32 * IN_FEAT];         // 16 KB
    const int tx = threadIdx.x;            // 0..63 (one wave per ty)
    const int ty = threadIdx.y;            // 0..3
    const int tid = ty * 64 + tx;
    const int r0 = blockIdx.x * 32;

    for (int i = tid; i < IN_FEAT * OUT_FEAT; i += 256) Ws[i] = W[i];
    for (int i = tid; i < 32 * IN_FEAT; i += 256) Xs[i] = x[r0 * IN_FEAT + i];
    __syncthreads();

    float acc[8];
    #pragma unroll
    for (int rr = 0; rr < 8; ++rr) acc[rr] = 0.0f;

    for (int k = 0; k < IN_FEAT; ++k) {
        const float wv = Ws[k * OUT_FEAT + tx];      // 64 lanes stride-1: 2-way alias, free
        #pragma unroll
        for (int rr = 0; rr < 8; ++rr)
            acc[rr] += Xs[(ty * 8 + rr) * IN_FEAT + k] * wv;  // wave-uniform: LDS broadcast
    }

    const float a_s = a[tx];
    const float a_t = a[OUT_FEAT + tx];
    #pragma unroll
    for (int rr = 0; rr < 8; ++rr) {
        const int row = r0 + ty * 8 + rr;
        Wh[row * OUT_FEAT + tx] = acc[rr];
        float ss = acc[rr] * a_s;
        float st = acc[rr] * a_t;
        #pragma unroll
        for (int off = 32; off; off >>= 1) {
            ss += __shfl_xor(ss, off, 64);
            st += __shfl_xor(st, off, 64);
        }
        if (tx == 0) { s_src[row] = ss; s_tgt[row] = st; }
    }
}

// Pass E1: e = leaky_relu(s_src[src] + s_tgt[tgt]); segment max into e_max_enc[tgt]
__global__ __launch_bounds__(256) void edge_max_kernel(
    const int* __restrict__ ei, const float* __restrict__ s_src,
    const float* __restrict__ s_tgt, float* __restrict__ e_buf,
    unsigned int* __restrict__ e_max_enc)
{
    int i = blockIdx.x * 256 + threadIdx.x;
    if (i >= N_EDGES) return;
    const int s = ei[i];
    const int t = ei[N_EDGES + i];
    float v = s_src[s] + s_tgt[t];
    v = (v >= 0.0f) ? v : LRELU_SLOPE * v;
    e_buf[i] = v;
    atomicMax(&e_max_enc[t], enc_f(v));
}

// Pass E2: e_exp = exp(e - max[tgt]); segment sum into e_sum[tgt]; e_buf overwritten
__global__ __launch_bounds__(256) void edge_exp_kernel(
    const int* __restrict__ ei, float* __restrict__ e_buf,
    const unsigned int* __restrict__ e_max_enc, float* __restrict__ e_sum)
{
    int i = blockIdx.x * 256 + threadIdx.x;
    if (i >= N_EDGES) return;
    const int t = ei[N_EDGES + i];
    const float m = dec_f(e_max_enc[t]);
    const float ex = expf(e_buf[i] - m);
    e_buf[i] = ex;
    atomicAdd(&e_sum[t], ex);
}

// Pass E3: wave-per-edge, lane=feature: h[tgt][f] += Wh[src][f] * alpha
__global__ __launch_bounds__(256) void edge_aggr_kernel(
    const int* __restrict__ ei, const float* __restrict__ e_buf,
    const float* __restrict__ e_sum, const float* __restrict__ Wh,
    float* __restrict__ h)
{
    const int gid = blockIdx.x * 256 + threadIdx.x;   // up to 102.4M < 2^31
    const int e = gid >> 6;
    const int f = gid & 63;
    if (e >= N_EDGES) return;
    const int s = ei[e];
    const int t = ei[N_EDGES + e];
    const float alpha = e_buf[e] / (e_sum[t] + EPS_DENOM);
    atomicAdd(&h[t * OUT_FEAT + f], Wh[s * OUT_FEAT + f] * alpha);
}

// ELU in place over the accumulated h (= d_out)
__global__ __launch_bounds__(256) void elu_kernel(float* __restrict__ h)
{
    int i = blockIdx.x * 256 + threadIdx.x;
    if (i < N_NODES * OUT_FEAT) {
        const float v = h[i];
        h[i] = (v > 0.0f) ? v : expm1f(v);
    }
}

extern "C" void kernel_launch(void* const* d_in, const int* in_sizes, int n_in,
                              void* d_out, int out_size, void* d_ws, size_t ws_size,
                              hipStream_t stream) {
    const float* x  = (const float*)d_in[0];
    const int*   ei = (const int*)d_in[1];     // int64 in reference -> int32 on device
    const float* W  = (const float*)d_in[2];
    const float* a  = (const float*)d_in[3];
    float* out = (float*)d_out;

    // workspace layout (floats): ~34 MB total
    float* ws = (float*)d_ws;
    float* Wh        = ws;                                  // 6.4M floats
    float* s_src     = Wh + (size_t)N_NODES * OUT_FEAT;     // 100k
    float* s_tgt     = s_src + N_NODES;                     // 100k
    float* e_buf     = s_tgt + N_NODES;                     // 1.6M
    unsigned int* e_max_enc = (unsigned int*)(e_buf + N_EDGES); // 100k
    float* e_sum     = (float*)(e_max_enc + N_NODES);       // 100k

    // h accumulates directly in d_out; zero it each call.
    hipMemsetAsync(d_out, 0, (size_t)N_NODES * OUT_FEAT * sizeof(float), stream);
    init_kernel<<<(N_NODES + 255) / 256, 256, 0, stream>>>(e_max_enc, e_sum);
    gemm_score_kernel<<<N_NODES / 32, dim3(64, 4), 0, stream>>>(x, W, a, Wh, s_src, s_tgt);
    edge_max_kernel<<<N_EDGES / 256, 256, 0, stream>>>(ei, s_src, s_tgt, e_buf, e_max_enc);
    edge_exp_kernel<<<N_EDGES / 256, 256, 0, stream>>>(ei, e_buf, e_max_enc, e_sum);
    edge_aggr_kernel<<<(N_EDGES * 64) / 256, 256, 0, stream>>>(ei, e_buf, e_sum, Wh, out);
    elu_kernel<<<(N_NODES * OUT_FEAT) / 256, 256, 0, stream>>>(out);
}

// Round 3
// 339.553 us; speedup vs baseline: 1.7446x; 1.7446x over previous
//
#include <hip/hip_runtime.h>

#define N_NODES 100000
#define N_EDGES 1600000
#define IN_FEAT 128
#define OUT_FEAT 64
#define LRELU_SLOPE 0.2f
#define EPS_DENOM 1e-16f
#define SCAN_BLOCKS ((N_NODES + 255) / 256)   // 391

__global__ __launch_bounds__(256) void zero_kernel(int* __restrict__ deg) {
    int i = blockIdx.x * 256 + threadIdx.x;
    if (i < N_NODES) deg[i] = 0;
}

// Wh = x @ W (100000x128 @ 128x64), fused per-row scores via wave reduce.
// Block 64x4; each block: 32 rows; each thread: 8 rows x 1 col.
__global__ __launch_bounds__(256) void gemm_score_kernel(
    const float* __restrict__ x, const float* __restrict__ W,
    const float* __restrict__ a, float* __restrict__ Wh,
    float* __restrict__ s_src, float* __restrict__ s_tgt)
{
    __shared__ __align__(16) float Ws[IN_FEAT * OUT_FEAT];   // 32 KB
    __shared__ __align__(16) float Xs[32 * IN_FEAT];         // 16 KB
    const int tx = threadIdx.x, ty = threadIdx.y;
    const int tid = ty * 64 + tx;
    const int r0 = blockIdx.x * 32;

    for (int i = tid; i < IN_FEAT * OUT_FEAT; i += 256) Ws[i] = W[i];
    for (int i = tid; i < 32 * IN_FEAT; i += 256) Xs[i] = x[r0 * IN_FEAT + i];
    __syncthreads();

    float acc[8];
    #pragma unroll
    for (int rr = 0; rr < 8; ++rr) acc[rr] = 0.0f;

    for (int k = 0; k < IN_FEAT; k += 4) {
        const float w0 = Ws[(k + 0) * OUT_FEAT + tx];
        const float w1 = Ws[(k + 1) * OUT_FEAT + tx];
        const float w2 = Ws[(k + 2) * OUT_FEAT + tx];
        const float w3 = Ws[(k + 3) * OUT_FEAT + tx];
        #pragma unroll
        for (int rr = 0; rr < 8; ++rr) {
            const float4 xv = *(const float4*)&Xs[(ty * 8 + rr) * IN_FEAT + k];
            acc[rr] += xv.x * w0 + xv.y * w1 + xv.z * w2 + xv.w * w3;
        }
    }

    const float a_s = a[tx];
    const float a_t = a[OUT_FEAT + tx];
    #pragma unroll
    for (int rr = 0; rr < 8; ++rr) {
        const int row = r0 + ty * 8 + rr;
        Wh[row * OUT_FEAT + tx] = acc[rr];
        float ss = acc[rr] * a_s;
        float st = acc[rr] * a_t;
        #pragma unroll
        for (int off = 32; off; off >>= 1) {
            ss += __shfl_xor(ss, off, 64);
            st += __shfl_xor(st, off, 64);
        }
        if (tx == 0) { s_src[row] = ss; s_tgt[row] = st; }
    }
}

__global__ __launch_bounds__(256) void hist_kernel(const int* __restrict__ ei,
                                                   int* __restrict__ deg) {
    int i = blockIdx.x * 256 + threadIdx.x;
    if (i < N_EDGES) atomicAdd(&deg[ei[N_EDGES + i]], 1);
}

// 3-kernel exclusive scan over deg[N_NODES] -> row_ptr
__global__ __launch_bounds__(256) void scan_block_kernel(const int* __restrict__ deg,
                                                         int* __restrict__ row_ptr,
                                                         int* __restrict__ bsum) {
    __shared__ int sd[256];
    const int t = threadIdx.x;
    const int i = blockIdx.x * 256 + t;
    const int v = (i < N_NODES) ? deg[i] : 0;
    sd[t] = v;
    __syncthreads();
    for (int off = 1; off < 256; off <<= 1) {
        int add = (t >= off) ? sd[t - off] : 0;
        __syncthreads();
        sd[t] += add;
        __syncthreads();
    }
    if (i < N_NODES) row_ptr[i] = sd[t] - v;   // exclusive
    if (t == 255) bsum[blockIdx.x] = sd[255];
}

__global__ __launch_bounds__(512) void scan_top_kernel(int* __restrict__ bsum) {
    __shared__ int sd[512];
    const int t = threadIdx.x;
    sd[t] = (t < SCAN_BLOCKS) ? bsum[t] : 0;
    __syncthreads();
    for (int off = 1; off < 512; off <<= 1) {
        int add = (t >= off) ? sd[t - off] : 0;
        __syncthreads();
        sd[t] += add;
        __syncthreads();
    }
    if (t < SCAN_BLOCKS) bsum[t] = sd[t];      // inclusive
}

__global__ __launch_bounds__(256) void scan_add_kernel(int* __restrict__ row_ptr,
                                                       const int* __restrict__ bsum,
                                                       int* __restrict__ cursor) {
    const int b = blockIdx.x;
    const int i = b * 256 + threadIdx.x;
    if (i < N_NODES) {
        int v = row_ptr[i] + (b > 0 ? bsum[b - 1] : 0);
        row_ptr[i] = v;
        cursor[i] = v;
    }
    if (i == 0) row_ptr[N_NODES] = N_EDGES;
}

// scatter edges into CSR segments; compute e = leaky_relu(s_src[s] + s_tgt[t])
__global__ __launch_bounds__(256) void scatter_kernel(
    const int* __restrict__ ei, const float* __restrict__ s_src,
    const float* __restrict__ s_tgt, int* __restrict__ cursor,
    int* __restrict__ sorted_src, float* __restrict__ sorted_e)
{
    int i = blockIdx.x * 256 + threadIdx.x;
    if (i >= N_EDGES) return;
    const int s = ei[i];
    const int t = ei[N_EDGES + i];
    float v = s_src[s] + s_tgt[t];
    v = (v >= 0.0f) ? v : LRELU_SLOPE * v;
    const int pos = atomicAdd(&cursor[t], 1);
    sorted_src[pos] = s;
    sorted_e[pos] = v;
}

// Fused: per-node softmax over its edge segment + weighted gather of Wh rows + ELU.
// One wave per node; lane = output feature.
__global__ __launch_bounds__(256) void node_aggr_kernel(
    const int* __restrict__ row_ptr, const int* __restrict__ sorted_src,
    const float* __restrict__ sorted_e, const float* __restrict__ Wh,
    float* __restrict__ out)
{
    const int wid = (blockIdx.x * 256 + threadIdx.x) >> 6;   // node id
    const int lane = threadIdx.x & 63;
    if (wid >= N_NODES) return;
    const int beg = row_ptr[wid];
    const int end = row_ptr[wid + 1];

    // pass 1: segment max (lanes stride the segment, coalesced)
    float m = -__builtin_inff();
    for (int i = beg + lane; i < end; i += 64) m = fmaxf(m, sorted_e[i]);
    #pragma unroll
    for (int off = 32; off; off >>= 1) m = fmaxf(m, __shfl_xor(m, off, 64));

    // pass 2: segment sum of exp
    float sum = 0.0f;
    for (int i = beg + lane; i < end; i += 64) sum += expf(sorted_e[i] - m);
    #pragma unroll
    for (int off = 32; off; off >>= 1) sum += __shfl_xor(sum, off, 64);
    const float inv = 1.0f / (sum + EPS_DENOM);

    // pass 3: acc[f] = sum_e w_e * Wh[src_e][f]  (lane = f; 4 edges in flight)
    float acc = 0.0f;
    int e = beg;
    for (; e + 4 <= end; e += 4) {
        const int s0 = sorted_src[e], s1 = sorted_src[e + 1];
        const int s2 = sorted_src[e + 2], s3 = sorted_src[e + 3];
        const float w0 = expf(sorted_e[e] - m) * inv;
        const float w1 = expf(sorted_e[e + 1] - m) * inv;
        const float w2 = expf(sorted_e[e + 2] - m) * inv;
        const float w3 = expf(sorted_e[e + 3] - m) * inv;
        acc += w0 * Wh[(size_t)s0 * OUT_FEAT + lane];
        acc += w1 * Wh[(size_t)s1 * OUT_FEAT + lane];
        acc += w2 * Wh[(size_t)s2 * OUT_FEAT + lane];
        acc += w3 * Wh[(size_t)s3 * OUT_FEAT + lane];
    }
    for (; e < end; ++e) {
        const float w = expf(sorted_e[e] - m) * inv;
        acc += w * Wh[(size_t)sorted_src[e] * OUT_FEAT + lane];
    }

    out[(size_t)wid * OUT_FEAT + lane] = (acc > 0.0f) ? acc : expm1f(acc);
}

extern "C" void kernel_launch(void* const* d_in, const int* in_sizes, int n_in,
                              void* d_out, int out_size, void* d_ws, size_t ws_size,
                              hipStream_t stream) {
    const float* x  = (const float*)d_in[0];
    const int*   ei = (const int*)d_in[1];     // int64 in reference -> int32 on device
    const float* W  = (const float*)d_in[2];
    const float* a  = (const float*)d_in[3];
    float* out = (float*)d_out;

    // workspace layout (~41 MB)
    char* p = (char*)d_ws;
    float* Wh         = (float*)p;  p += (size_t)N_NODES * OUT_FEAT * 4;
    float* s_src      = (float*)p;  p += (size_t)N_NODES * 4;
    float* s_tgt      = (float*)p;  p += (size_t)N_NODES * 4;
    int*   deg        = (int*)p;    p += (size_t)N_NODES * 4;
    int*   row_ptr    = (int*)p;    p += (size_t)(N_NODES + 1) * 4;
    int*   cursor     = (int*)p;    p += (size_t)N_NODES * 4;
    int*   bsum       = (int*)p;    p += (size_t)SCAN_BLOCKS * 4;
    p = (char*)(((size_t)p + 15) & ~(size_t)15);
    int*   sorted_src = (int*)p;    p += (size_t)N_EDGES * 4;
    float* sorted_e   = (float*)p;  p += (size_t)N_EDGES * 4;

    zero_kernel<<<SCAN_BLOCKS, 256, 0, stream>>>(deg);
    gemm_score_kernel<<<N_NODES / 32, dim3(64, 4), 0, stream>>>(x, W, a, Wh, s_src, s_tgt);
    hist_kernel<<<(N_EDGES + 255) / 256, 256, 0, stream>>>(ei, deg);
    scan_block_kernel<<<SCAN_BLOCKS, 256, 0, stream>>>(deg, row_ptr, bsum);
    scan_top_kernel<<<1, 512, 0, stream>>>(bsum);
    scan_add_kernel<<<SCAN_BLOCKS, 256, 0, stream>>>(row_ptr, bsum, cursor);
    scatter_kernel<<<(N_EDGES + 255) / 256, 256, 0, stream>>>(ei, s_src, s_tgt, cursor,
                                                              sorted_src, sorted_e);
    node_aggr_kernel<<<(N_NODES * 64 + 255) / 256, 256, 0, stream>>>(row_ptr, sorted_src,
                                                                     sorted_e, Wh, out);
}

// Round 4
// 316.819 us; speedup vs baseline: 1.8698x; 1.0718x over previous
//
#include <hip/hip_runtime.h>

#define N_NODES 100000
#define N_EDGES 1600000
#define IN_FEAT 128
#define OUT_FEAT 64
#define LRELU_SLOPE 0.2f
#define EPS_DENOM 1e-16f
#define SCAN_BLOCKS ((N_NODES + 255) / 256)   // 391

#define BKT_SHIFT 7
#define BKT_NODES 128                          // nodes per coarse bucket
#define N_BKT ((N_NODES + BKT_NODES - 1) / BKT_NODES)   // 782
#define N_SUB 8                                // XCD-local sub-regions per bucket
#define SUB_CAP 384                            // mean 256, ~8 sigma headroom

__global__ __launch_bounds__(256) void init_kernel(int* __restrict__ deg,
                                                   int* __restrict__ cursorA) {
    int i = blockIdx.x * 256 + threadIdx.x;
    if (i < N_NODES) deg[i] = 0;
    if (i < N_BKT * N_SUB) cursorA[i] = i * SUB_CAP;   // static sub-region starts
}

// Wh = x @ W (100000x128 @ 128x64), fused per-row scores via wave reduce.
__global__ __launch_bounds__(256) void gemm_score_kernel(
    const float* __restrict__ x, const float* __restrict__ W,
    const float* __restrict__ a, float* __restrict__ Wh,
    float* __restrict__ s_src, float* __restrict__ s_tgt)
{
    __shared__ __align__(16) float Ws[IN_FEAT * OUT_FEAT];   // 32 KB
    __shared__ __align__(16) float Xs[32 * IN_FEAT];         // 16 KB
    const int tx = threadIdx.x, ty = threadIdx.y;
    const int tid = ty * 64 + tx;
    const int r0 = blockIdx.x * 32;

    for (int i = tid; i < IN_FEAT * OUT_FEAT; i += 256) Ws[i] = W[i];
    for (int i = tid; i < 32 * IN_FEAT; i += 256) Xs[i] = x[r0 * IN_FEAT + i];
    __syncthreads();

    float acc[8];
    #pragma unroll
    for (int rr = 0; rr < 8; ++rr) acc[rr] = 0.0f;

    for (int k = 0; k < IN_FEAT; k += 4) {
        const float w0 = Ws[(k + 0) * OUT_FEAT + tx];
        const float w1 = Ws[(k + 1) * OUT_FEAT + tx];
        const float w2 = Ws[(k + 2) * OUT_FEAT + tx];
        const float w3 = Ws[(k + 3) * OUT_FEAT + tx];
        #pragma unroll
        for (int rr = 0; rr < 8; ++rr) {
            const float4 xv = *(const float4*)&Xs[(ty * 8 + rr) * IN_FEAT + k];
            acc[rr] += xv.x * w0 + xv.y * w1 + xv.z * w2 + xv.w * w3;
        }
    }

    const float a_s = a[tx];
    const float a_t = a[OUT_FEAT + tx];
    #pragma unroll
    for (int rr = 0; rr < 8; ++rr) {
        const int row = r0 + ty * 8 + rr;
        Wh[row * OUT_FEAT + tx] = acc[rr];
        float ss = acc[rr] * a_s;
        float st = acc[rr] * a_t;
        #pragma unroll
        for (int off = 32; off; off >>= 1) {
            ss += __shfl_xor(ss, off, 64);
            st += __shfl_xor(st, off, 64);
        }
        if (tx == 0) { s_src[row] = ss; s_tgt[row] = st; }
    }
}

// Phase A: edge -> coarse bucket (XCD-local sub-region), fused degree histogram.
// Packs (src[17b] | tgt_low[7b]<<17, e) into int2.
__global__ __launch_bounds__(256) void scatter_coarse_kernel(
    const int* __restrict__ ei, const float* __restrict__ s_src,
    const float* __restrict__ s_tgt, int* __restrict__ deg,
    int* __restrict__ cursorA, int2* __restrict__ bucketsA)
{
    int i = blockIdx.x * 256 + threadIdx.x;
    if (i >= N_EDGES) return;
    const int s = ei[i];
    const int t = ei[N_EDGES + i];
    float v = s_src[s] + s_tgt[t];
    v = (v >= 0.0f) ? v : LRELU_SLOPE * v;
    atomicAdd(&deg[t], 1);
    const int bkt = t >> BKT_SHIFT;
    const int sub = blockIdx.x & (N_SUB - 1);          // ~XCD id under RR dispatch
    const int pos = atomicAdd(&cursorA[bkt * N_SUB + sub], 1);
    bucketsA[pos] = make_int2(s | ((t & (BKT_NODES - 1)) << 17), __float_as_int(v));
}

// 3-kernel exclusive scan over deg -> row_ptr
__global__ __launch_bounds__(256) void scan_block_kernel(const int* __restrict__ deg,
                                                         int* __restrict__ row_ptr,
                                                         int* __restrict__ bsum) {
    __shared__ int sd[256];
    const int t = threadIdx.x;
    const int i = blockIdx.x * 256 + t;
    const int v = (i < N_NODES) ? deg[i] : 0;
    sd[t] = v;
    __syncthreads();
    for (int off = 1; off < 256; off <<= 1) {
        int add = (t >= off) ? sd[t - off] : 0;
        __syncthreads();
        sd[t] += add;
        __syncthreads();
    }
    if (i < N_NODES) row_ptr[i] = sd[t] - v;   // exclusive
    if (t == 255) bsum[blockIdx.x] = sd[255];
}

__global__ __launch_bounds__(512) void scan_top_kernel(int* __restrict__ bsum) {
    __shared__ int sd[512];
    const int t = threadIdx.x;
    sd[t] = (t < SCAN_BLOCKS) ? bsum[t] : 0;
    __syncthreads();
    for (int off = 1; off < 512; off <<= 1) {
        int add = (t >= off) ? sd[t - off] : 0;
        __syncthreads();
        sd[t] += add;
        __syncthreads();
    }
    if (t < SCAN_BLOCKS) bsum[t] = sd[t];      // inclusive
}

__global__ __launch_bounds__(256) void scan_add_kernel(int* __restrict__ row_ptr,
                                                       const int* __restrict__ bsum) {
    const int b = blockIdx.x;
    const int i = b * 256 + threadIdx.x;
    if (i < N_NODES) row_ptr[i] += (b > 0 ? bsum[b - 1] : 0);
    if (i == 0) row_ptr[N_NODES] = N_EDGES;
}

// Phase B: one block per bucket; deposit edges at final CSR positions.
// Output window per block is contiguous (~16 KB) -> coalesced in one L2.
__global__ __launch_bounds__(256) void sort_bucket_kernel(
    const int* __restrict__ cursorA, const int2* __restrict__ bucketsA,
    const int* __restrict__ row_ptr, int2* __restrict__ sorted_se)
{
    __shared__ int cur[BKT_NODES];
    const int b = blockIdx.x;
    const int t0 = b * BKT_NODES;
    const int tid = threadIdx.x;
    if (tid < BKT_NODES) {
        const int t = t0 + tid;
        cur[tid] = (t < N_NODES) ? row_ptr[t] : 0;
    }
    __syncthreads();
    #pragma unroll
    for (int s = 0; s < N_SUB; ++s) {
        const int base = (b * N_SUB + s) * SUB_CAP;
        const int cnt = cursorA[b * N_SUB + s] - base;
        for (int k = tid; k < cnt; k += 256) {
            const int2 pk = bucketsA[base + k];
            const int src = pk.x & 0x1FFFF;
            const int tl  = (pk.x >> 17) & (BKT_NODES - 1);
            const int pos = atomicAdd(&cur[tl], 1);   // LDS atomic
            sorted_se[pos] = make_int2(src, pk.y);
        }
    }
}

// Fused: per-node softmax over its segment + weighted gather of Wh rows + ELU.
// One wave per node; lane = output feature.
__global__ __launch_bounds__(256) void node_aggr_kernel(
    const int* __restrict__ row_ptr, const int2* __restrict__ sorted_se,
    const float* __restrict__ Wh, float* __restrict__ out)
{
    const int wid = (blockIdx.x * 256 + threadIdx.x) >> 6;   // node id
    const int lane = threadIdx.x & 63;
    if (wid >= N_NODES) return;
    const int beg = row_ptr[wid];
    const int end = row_ptr[wid + 1];

    // pass 1: segment max
    float m = -__builtin_inff();
    for (int i = beg + lane; i < end; i += 64)
        m = fmaxf(m, __int_as_float(sorted_se[i].y));
    #pragma unroll
    for (int off = 32; off; off >>= 1) m = fmaxf(m, __shfl_xor(m, off, 64));

    // pass 2: segment sum of exp
    float sum = 0.0f;
    for (int i = beg + lane; i < end; i += 64)
        sum += expf(__int_as_float(sorted_se[i].y) - m);
    #pragma unroll
    for (int off = 32; off; off >>= 1) sum += __shfl_xor(sum, off, 64);
    const float inv = 1.0f / (sum + EPS_DENOM);

    // pass 3: acc[f] = sum_e w_e * Wh[src_e][f]  (lane = f; 4 edges in flight)
    float acc = 0.0f;
    int e = beg;
    for (; e + 4 <= end; e += 4) {
        const int2 p0 = sorted_se[e],     p1 = sorted_se[e + 1];
        const int2 p2 = sorted_se[e + 2], p3 = sorted_se[e + 3];
        const float w0 = expf(__int_as_float(p0.y) - m) * inv;
        const float w1 = expf(__int_as_float(p1.y) - m) * inv;
        const float w2 = expf(__int_as_float(p2.y) - m) * inv;
        const float w3 = expf(__int_as_float(p3.y) - m) * inv;
        acc += w0 * Wh[(size_t)p0.x * OUT_FEAT + lane];
        acc += w1 * Wh[(size_t)p1.x * OUT_FEAT + lane];
        acc += w2 * Wh[(size_t)p2.x * OUT_FEAT + lane];
        acc += w3 * Wh[(size_t)p3.x * OUT_FEAT + lane];
    }
    for (; e < end; ++e) {
        const int2 pk = sorted_se[e];
        const float w = expf(__int_as_float(pk.y) - m) * inv;
        acc += w * Wh[(size_t)pk.x * OUT_FEAT + lane];
    }

    out[(size_t)wid * OUT_FEAT + lane] = (acc > 0.0f) ? acc : expm1f(acc);
}

extern "C" void kernel_launch(void* const* d_in, const int* in_sizes, int n_in,
                              void* d_out, int out_size, void* d_ws, size_t ws_size,
                              hipStream_t stream) {
    const float* x  = (const float*)d_in[0];
    const int*   ei = (const int*)d_in[1];     // int64 in reference -> int32 on device
    const float* W  = (const float*)d_in[2];
    const float* a  = (const float*)d_in[3];
    float* out = (float*)d_out;

    // workspace layout (~59 MB)
    char* p = (char*)d_ws;
    float* Wh         = (float*)p;  p += (size_t)N_NODES * OUT_FEAT * 4;       // 25.6 MB
    float* s_src      = (float*)p;  p += (size_t)N_NODES * 4;
    float* s_tgt      = (float*)p;  p += (size_t)N_NODES * 4;
    int*   deg        = (int*)p;    p += (size_t)N_NODES * 4;
    int*   row_ptr    = (int*)p;    p += (size_t)(N_NODES + 1) * 4;
    int*   bsum       = (int*)p;    p += (size_t)SCAN_BLOCKS * 4;
    int*   cursorA    = (int*)p;    p += (size_t)N_BKT * N_SUB * 4;
    p = (char*)(((size_t)p + 15) & ~(size_t)15);
    int2*  bucketsA   = (int2*)p;   p += (size_t)N_BKT * N_SUB * SUB_CAP * 8;  // 19.2 MB
    int2*  sorted_se  = (int2*)p;   p += (size_t)N_EDGES * 8;                  // 12.8 MB

    init_kernel<<<SCAN_BLOCKS, 256, 0, stream>>>(deg, cursorA);
    gemm_score_kernel<<<N_NODES / 32, dim3(64, 4), 0, stream>>>(x, W, a, Wh, s_src, s_tgt);
    scatter_coarse_kernel<<<(N_EDGES + 255) / 256, 256, 0, stream>>>(ei, s_src, s_tgt,
                                                                     deg, cursorA, bucketsA);
    scan_block_kernel<<<SCAN_BLOCKS, 256, 0, stream>>>(deg, row_ptr, bsum);
    scan_top_kernel<<<1, 512, 0, stream>>>(bsum);
    scan_add_kernel<<<SCAN_BLOCKS, 256, 0, stream>>>(row_ptr, bsum);
    sort_bucket_kernel<<<N_BKT, 256, 0, stream>>>(cursorA, bucketsA, row_ptr, sorted_se);
    node_aggr_kernel<<<(N_NODES * 64 + 255) / 256, 256, 0, stream>>>(row_ptr, sorted_se,
                                                                     Wh, out);
}